// Round 7
// baseline (69.196 us; speedup 1.0000x reference)
//
#include <hip/hip_runtime.h>
#include <math.h>

// V=4 views, N=8192 points, 6 directed chamfer terms (pair p rows=view pi, min over view pj)
#define VNUM   4
#define NPAIRS 6
#define BLK    256
#define QTILE  2048   // b-points per block (quarter of N)
#define CHUNK  1024   // b-points staged per LDS phase (32 KB)

using short8  = __attribute__((ext_vector_type(8)))  short;
using f32x16  = __attribute__((ext_vector_type(16))) float;

__device__ inline unsigned short f2bf(float x) {           // RNE to bf16
    unsigned u = __float_as_uint(x);
    return (unsigned short)((u + 0x7FFFu + ((u >> 16) & 1u)) >> 16);
}
__device__ inline float bf2f(unsigned short b) {
    return __uint_as_float(((unsigned)b) << 16);
}

// world-transform + hi/lo bf16 split (s = |p|^2)
__device__ inline void xform_split(const float* __restrict__ P,
                                   float px, float py, float pz,
                                   unsigned short& xh, unsigned short& xl,
                                   unsigned short& yh, unsigned short& yl,
                                   unsigned short& zh, unsigned short& zl,
                                   unsigned short& sh, unsigned short& sl) {
    float x = fmaf(P[0], px, fmaf(P[1], py, fmaf(P[2],  pz, P[3])));
    float y = fmaf(P[4], px, fmaf(P[5], py, fmaf(P[6],  pz, P[7])));
    float z = fmaf(P[8], px, fmaf(P[9], py, fmaf(P[10], pz, P[11])));
    float s = fmaf(x, x, fmaf(y, y, z * z));
    xh = f2bf(x); xl = f2bf(x - bf2f(xh));
    yh = f2bf(y); yl = f2bf(y - bf2f(yh));
    zh = f2bf(z); zl = f2bf(z - bf2f(zh));
    sh = f2bf(s); sl = f2bf(s - bf2f(sh));
}

// Fully fused: per-block fragment build (A in regs, B slice in LDS), MFMA
// min-accumulate (plain fminf only -- NO inline asm on MFMA outputs), probe-
// calibrated C/D mapping, atomicMin combine, last-block-of-group finalize.
// dot(Afrag[a],Bfrag[b]) = |a|^2+|b|^2-2*(a_hi+a_lo).(b_hi+b_lo).
__global__ __launch_bounds__(BLK, 4)
void fused_kernel(const float* __restrict__ pts,
                  const float* __restrict__ poses,
                  unsigned int* __restrict__ minbuf,
                  unsigned int* __restrict__ done,
                  float* __restrict__ out, int N, float scale) {
    __shared__ short8 sbuf[CHUNK * 2];            // 32 KB: [hi x1024][lo x1024]
    __shared__ float fred[BLK / 64];
    __shared__ unsigned s_old;
    const int p  = blockIdx.z;
    const int pi = (p < 3) ? 0 : ((p < 5) ? 1 : 2);
    const int pj = (p < 3) ? (p + 1) : ((p < 5) ? (p - 1) : 3);
    const int tid  = threadIdx.x;
    const int w    = tid >> 6;
    const int l    = tid & 63;
    const int col  = l & 31;
    const int half = l >> 5;
    const int abase = (blockIdx.y * 4 + w) * 64;  // 64 a-rows per wave
    const int b0    = blockIdx.x * QTILE;
    const float* Pi = poses + pi * 16;
    const float* Pj = poses + pj * 16;
    const short one = (short)0x3F80;

    // ---- A fragments for this lane's two a-points ----
    short8 A0, A1;
#pragma unroll
    for (int q = 0; q < 2; ++q) {
        int r = pi * N + abase + col + q * 32;
        unsigned short xh, xl, yh, yl, zh, zl, sh, sl;
        xform_split(Pi, pts[r*3], pts[r*3+1], pts[r*3+2],
                    xh, xl, yh, yl, zh, zl, sh, sl);
        short8 e07, e8f;
        e07[0]=(short)xh; e07[1]=(short)yh; e07[2]=(short)zh; e07[3]=(short)xh;
        e07[4]=(short)yh; e07[5]=(short)zh; e07[6]=(short)xl; e07[7]=(short)yl;
        e8f[0]=(short)zl; e8f[1]=(short)sh; e8f[2]=(short)sl; e8f[3]=one;
        e8f[4]=one;       e8f[5]=(short)xl; e8f[6]=(short)yl; e8f[7]=(short)zl;
        short8 Av; if (half) Av = e8f; else Av = e07;
        if (q == 0) A0 = Av; else A1 = Av;
    }

    f32x16 m0, m1, zz;
#pragma unroll
    for (int i = 0; i < 16; ++i) { m0[i] = 3.402823466e38f; m1[i] = 3.402823466e38f; zz[i] = 0.0f; }

    for (int c = 0; c < QTILE / CHUNK; ++c) {
        __syncthreads();                          // prior phase fully consumed
        const float* bp = pts + ((size_t)(pj * N + b0 + c * CHUNK)) * 3;
#pragma unroll
        for (int k = 0; k < CHUNK / BLK; ++k) {   // 4 b-points per thread
            int i = k * BLK + tid;
            unsigned short xh, xl, yh, yl, zh, zl, sh, sl;
            xform_split(Pj, bp[i*3], bp[i*3+1], bp[i*3+2],
                        xh, xl, yh, yl, zh, zl, sh, sl);
            // -2 * bf16 piece is exact (power-of-two scale)
            short bxh=(short)f2bf(-2.0f*bf2f(xh)), byh=(short)f2bf(-2.0f*bf2f(yh)),
                  bzh=(short)f2bf(-2.0f*bf2f(zh));
            short bxl=(short)f2bf(-2.0f*bf2f(xl)), byl=(short)f2bf(-2.0f*bf2f(yl)),
                  bzl=(short)f2bf(-2.0f*bf2f(zl));
            short8 hi8, lo8;
            hi8[0]=bxh; hi8[1]=byh; hi8[2]=bzh; hi8[3]=bxl;
            hi8[4]=byl; hi8[5]=bzl; hi8[6]=bxh; hi8[7]=byh;
            lo8[0]=bzh; lo8[1]=one; lo8[2]=one; lo8[3]=(short)sh;
            lo8[4]=(short)sl; lo8[5]=bxl; lo8[6]=byl; lo8[7]=bzl;
            sbuf[i] = hi8; sbuf[CHUNK + i] = lo8;
        }
        __syncthreads();

        const short8* bsel = half ? (sbuf + CHUNK) : sbuf;
        for (int t = 0; t < CHUNK / 32; t += 2) { // 2 b-tiles per iteration
            short8 B0 = bsel[t * 32 + col];
            short8 B1 = bsel[(t + 1) * 32 + col];
            f32x16 d0 = __builtin_amdgcn_mfma_f32_32x32x16_bf16(A0, B0, zz, 0, 0, 0);
            f32x16 d1 = __builtin_amdgcn_mfma_f32_32x32x16_bf16(A0, B1, zz, 0, 0, 0);
#pragma unroll
            for (int i = 0; i < 16; ++i) m0[i] = fminf(m0[i], fminf(d0[i], d1[i]));
            d0 = __builtin_amdgcn_mfma_f32_32x32x16_bf16(A1, B0, zz, 0, 0, 0);
            d1 = __builtin_amdgcn_mfma_f32_32x32x16_bf16(A1, B1, zz, 0, 0, 0);
#pragma unroll
            for (int i = 0; i < 16; ++i) m1[i] = fminf(m1[i], fminf(d0[i], d1[i]));
        }
    }

    // ---- layout probe: A[m][k]=m broadcast, B[k][n]=1 -> D[m][n]=16m ----
    short8 pa, po;
    unsigned short lv = f2bf((float)col);
#pragma unroll
    for (int i = 0; i < 8; ++i) { pa[i] = (short)lv; po[i] = one; }
    f32x16 pr = __builtin_amdgcn_mfma_f32_32x32x16_bf16(pa, po, zz, 0, 0, 0);
    int rowidx[16];
#pragma unroll
    for (int i = 0; i < 16; ++i) rowidx[i] = (int)(pr[i] * 0.0625f + 0.5f);
    const bool row_on_lane = (rowidx[0] == rowidx[1]);   // wave-uniform

    unsigned int* mb = minbuf + (size_t)p * N;
    if (!row_on_lane) {
        // cols on lanes: butterfly min across the 32 lanes of each half
#pragma unroll
        for (int off = 1; off <= 16; off <<= 1) {
#pragma unroll
            for (int i = 0; i < 16; ++i) {
                m0[i] = fminf(m0[i], __shfl_xor(m0[i], off, 64));
                m1[i] = fminf(m1[i], __shfl_xor(m1[i], off, 64));
            }
        }
        if (col == 0) {
#pragma unroll
            for (int r = 0; r < 16; ++r) {
                atomicMin(&mb[abase + rowidx[r]],
                          __float_as_uint(fmaxf(m0[r], 0.0f)));
                atomicMin(&mb[abase + 32 + rowidx[r]],
                          __float_as_uint(fmaxf(m1[r], 0.0f)));
            }
        }
    } else {
        // rows on lanes: min over regs in-lane, then across halves
        float v0 = m0[0], v1 = m1[0];
#pragma unroll
        for (int i = 1; i < 16; ++i) { v0 = fminf(v0, m0[i]); v1 = fminf(v1, m1[i]); }
        v0 = fminf(v0, __shfl_xor(v0, 32, 64));
        v1 = fminf(v1, __shfl_xor(v1, 32, 64));
        if (half == 0) {
            atomicMin(&mb[abase + col],      __float_as_uint(fmaxf(v0, 0.0f)));
            atomicMin(&mb[abase + 32 + col], __float_as_uint(fmaxf(v1, 0.0f)));
        }
    }

    // ---- last-of-4-blocks finalizes this (pair, 256-row chunk) ----
    __threadfence();                              // mins visible before count
    __syncthreads();
    if (tid == 0) s_old = atomicAdd(&done[p * 32 + blockIdx.y], 1u);
    __syncthreads();
    if (s_old == 0x7F7F7F7Fu + 3u) {              // done was memset to 0x7F
        int row = blockIdx.y * 256 + tid;
        // coherent read: atomicMin with the init value returns old, changes nothing
        unsigned v = atomicMin(&mb[row], 0x7F7F7F7Fu);
        float d = sqrtf(__uint_as_float(v));
#pragma unroll
        for (int off = 32; off >= 1; off >>= 1)
            d += __shfl_down(d, off, 64);
        if (l == 0) fred[w] = d;
        __syncthreads();
        if (tid == 0) {
            float s = 0.0f;
#pragma unroll
            for (int wv = 0; wv < BLK / 64; ++wv) s += fred[wv];
            atomicAdd(out, s * scale);
        }
    }
}

extern "C" void kernel_launch(void* const* d_in, const int* in_sizes, int n_in,
                              void* d_out, int out_size, void* d_ws, size_t ws_size,
                              hipStream_t stream) {
    const float* points = (const float*)d_in[0];   // V x N x 3 fp32
    const float* poses  = (const float*)d_in[1];   // V x 4 x 4 fp32
    float* out = (float*)d_out;                    // scalar fp32

    const int N = in_sizes[0] / (VNUM * 3);        // 8192

    // ws: minbuf uint[6*N] (192KB) | done uint[192]
    unsigned int* minbuf = (unsigned int*)d_ws;
    unsigned int* done   = minbuf + (size_t)NPAIRS * N;

    // 0x7F fill: minbuf -> 0x7F7F7F7F (~3.39e38, > any d^2); done -> base for +4 count
    hipMemsetAsync(minbuf, 0x7F, ((size_t)NPAIRS * N + NPAIRS * 32) * 4, stream);
    hipMemsetAsync(out, 0, sizeof(float), stream);

    dim3 grid(N / QTILE, N / 256, NPAIRS);         // 4 x 32 x 6 = 768 blocks
    fused_kernel<<<grid, BLK, 0, stream>>>(points, poses, minbuf, done, out, N,
                                           1.0f / (6.0f * (float)N));
}